// Round 2
// baseline (8614.223 us; speedup 1.0000x reference)
//
#include <hip/hip_runtime.h>
#include <stdint.h>

#define NN 50000
#define NE 800000
#define LN_EPS 1e-5f

__device__ __forceinline__ float bfbits2f(unsigned short u) {
  return __uint_as_float(((unsigned)u) << 16);
}
__device__ __forceinline__ unsigned short f2bfbits(float f) {
  unsigned u = __float_as_uint(f);
  u += 0x7FFFu + ((u >> 16) & 1u);   // round-to-nearest-even
  return (unsigned short)(u >> 16);
}
__device__ __forceinline__ float4 ld4f(const void* p, size_t i, bool f32) {
  if (f32) return *reinterpret_cast<const float4*>((const float*)p + i);
  ushort4 r = *reinterpret_cast<const ushort4*>((const unsigned short*)p + i);
  return make_float4(bfbits2f(r.x), bfbits2f(r.y), bfbits2f(r.z), bfbits2f(r.w));
}
__device__ __forceinline__ float ld1f(const void* p, size_t i, bool f32) {
  return f32 ? ((const float*)p)[i] : bfbits2f(((const unsigned short*)p)[i]);
}

// Decide whether float tensors are fp32 (flag=1) or bf16 (flag=0).
// fp32 data read as ushorts: even halves are mantissa garbage -> ~40% decode
// to |bf16| > 1e6 (or NaN). bf16 N(0,1) data: 0% do.
__global__ void detect_kernel(const void* feat, int* flag) {
  int cnt = 0;
  const unsigned short* u = (const unsigned short*)feat;
  for (int i = threadIdx.x; i < 512; i += 64) {
    float v = bfbits2f(u[i]);
    if (!(fabsf(v) < 1e6f)) cnt++;  // counts NaN too
  }
#pragma unroll
  for (int off = 32; off > 0; off >>= 1) cnt += __shfl_down(cnt, off, 64);
  if (threadIdx.x == 0) flag[0] = (cnt > 8) ? 1 : 0;
}

// One 64-lane group per edge, 4 feats/lane. agg[dst] += h[src] / deg[dst]
__global__ void scatter_mean_kernel(const void* __restrict__ h,
                                    const int* __restrict__ src,
                                    const int* __restrict__ dst,
                                    const void* __restrict__ indeg,
                                    float* __restrict__ agg,
                                    const int* __restrict__ dtflag,
                                    int h_always_f32) {
  bool inf32 = dtflag[0] != 0;
  bool hf32 = h_always_f32 || inf32;
  int t = blockIdx.x * blockDim.x + threadIdx.x;
  int e = t >> 6;
  if (e >= NE) return;
  int lane = t & 63;
  int s = src[e], d = dst[e];
  float rdeg = 1.0f / ld1f(indeg, d, inf32);
  float4 v = ld4f(h, (size_t)s * 256 + lane * 4, hf32);
  float* ap = agg + (size_t)d * 256 + lane * 4;
  atomicAdd(ap + 0, v.x * rdeg);
  atomicAdd(ap + 1, v.y * rdeg);
  atomicAdd(ap + 2, v.z * rdeg);
  atomicAdd(ap + 3, v.w * rdeg);
}

// C = A1 @ B1 + A2(f32) @ B2 + bias.  M=NN, K=256 per phase.
// 64x64 tile, BK=16, 256 threads, 4x4 per thread, fp32 accumulate.
template <int N, bool LAST>
__global__ __launch_bounds__(256) void gemm_dual_kernel(
    const void* __restrict__ A1, const float* __restrict__ A2,
    const void* __restrict__ B1, const void* __restrict__ B2,
    const void* __restrict__ bias, void* __restrict__ out,
    const int* __restrict__ dtflag, int a1_always_f32) {
  bool inf32 = dtflag[0] != 0;
  bool a1f32 = a1_always_f32 || inf32;
  __shared__ __align__(16) float As[16][68];
  __shared__ __align__(16) float Bs[16][68];
  const int tid = threadIdx.x;
  const int row0 = blockIdx.x * 64;
  const int col0 = blockIdx.y * 64;
  const int ty = tid >> 4;
  const int tx = tid & 15;
  const int lm = tid >> 2;
  const int lk = (tid & 3) * 4;
  const int bk = tid >> 4;
  const int bn = (tid & 15) * 4;

  float acc[4][4] = {};
  for (int phase = 0; phase < 2; ++phase) {
    const void* Bp = phase ? B2 : B1;
    for (int kb = 0; kb < 256; kb += 16) {
      int grow = row0 + lm;
      float4 a = make_float4(0.f, 0.f, 0.f, 0.f);
      if (grow < NN) {
        if (phase == 0)
          a = ld4f(A1, (size_t)grow * 256 + kb + lk, a1f32);
        else
          a = *reinterpret_cast<const float4*>(A2 + (size_t)grow * 256 + kb + lk);
      }
      As[lk + 0][lm] = a.x; As[lk + 1][lm] = a.y;
      As[lk + 2][lm] = a.z; As[lk + 3][lm] = a.w;
      float4 b = ld4f(Bp, (size_t)(kb + bk) * N + col0 + bn, inf32);
      Bs[bk][bn + 0] = b.x; Bs[bk][bn + 1] = b.y;
      Bs[bk][bn + 2] = b.z; Bs[bk][bn + 3] = b.w;
      __syncthreads();
#pragma unroll
      for (int k = 0; k < 16; ++k) {
        float4 av = *reinterpret_cast<const float4*>(&As[k][ty * 4]);
        float4 bv = *reinterpret_cast<const float4*>(&Bs[k][tx * 4]);
        float aa[4] = {av.x, av.y, av.z, av.w};
        float bb[4] = {bv.x, bv.y, bv.z, bv.w};
#pragma unroll
        for (int i = 0; i < 4; ++i)
#pragma unroll
          for (int j = 0; j < 4; ++j) acc[i][j] += aa[i] * bb[j];
      }
      __syncthreads();
    }
  }
  float bc[4];
#pragma unroll
  for (int j = 0; j < 4; ++j) bc[j] = ld1f(bias, col0 + tx * 4 + j, inf32);
#pragma unroll
  for (int i = 0; i < 4; ++i) {
    int r = row0 + ty * 4 + i;
    if (r >= NN) break;
    float o0 = acc[i][0] + bc[0], o1 = acc[i][1] + bc[1];
    float o2 = acc[i][2] + bc[2], o3 = acc[i][3] + bc[3];
    size_t idx = (size_t)r * N + col0 + tx * 4;
    if (LAST && !inf32) {
      ushort4 v = {f2bfbits(o0), f2bfbits(o1), f2bfbits(o2), f2bfbits(o3)};
      *reinterpret_cast<ushort4*>((unsigned short*)out + idx) = v;
    } else {
      float4 v = {o0, o1, o2, o3};
      *reinterpret_cast<float4*>((float*)out + idx) = v;
    }
  }
}

// In-place LN over 256 cols + ReLU on fp32 buffer. One wave per row.
__global__ void ln_relu_kernel(float* __restrict__ buf,
                               const void* __restrict__ g,
                               const void* __restrict__ be,
                               const int* __restrict__ dtflag) {
  bool inf32 = dtflag[0] != 0;
  int row = blockIdx.x * 4 + (threadIdx.x >> 6);
  int lane = threadIdx.x & 63;
  float* p = buf + (size_t)row * 256 + lane * 4;
  float4 v = *reinterpret_cast<const float4*>(p);
  float s = v.x + v.y + v.z + v.w;
  float sq = v.x * v.x + v.y * v.y + v.z * v.z + v.w * v.w;
#pragma unroll
  for (int off = 32; off > 0; off >>= 1) {
    s += __shfl_down(s, off, 64);
    sq += __shfl_down(sq, off, 64);
  }
  s = __shfl(s, 0, 64);
  sq = __shfl(sq, 0, 64);
  float mu = s * (1.0f / 256.0f);
  float var = fmaxf(sq * (1.0f / 256.0f) - mu * mu, 0.0f);
  float rs = rsqrtf(var + LN_EPS);
  float vv[4] = {v.x, v.y, v.z, v.w};
  float4 o;
#pragma unroll
  for (int i = 0; i < 4; ++i) {
    int c = lane * 4 + i;
    float x = (vv[i] - mu) * rs * ld1f(g, c, inf32) + ld1f(be, c, inf32);
    (&o.x)[i] = fmaxf(x, 0.0f);
  }
  *reinterpret_cast<float4*>(p) = o;
}

extern "C" void kernel_launch(void* const* d_in, const int* in_sizes, int n_in,
                              void* d_out, int out_size, void* d_ws, size_t ws_size,
                              hipStream_t stream) {
  const void* feat = d_in[0];
  const int* ei = (const int*)d_in[1];
  const void* indeg = d_in[2];
  const void* ws0 = d_in[3]; const void* wn0 = d_in[4]; const void* b0 = d_in[5];
  const void* ws1 = d_in[6]; const void* wn1 = d_in[7]; const void* b1 = d_in[8];
  const void* ws2 = d_in[9]; const void* wn2 = d_in[10]; const void* b2 = d_in[11];
  const void* g0 = d_in[12]; const void* be0 = d_in[13];
  const void* g1 = d_in[14]; const void* be1 = d_in[15];
  const int* src = ei;
  const int* dst = ei + NE;

  float* agg = (float*)d_ws;                        // 51.2 MB
  float* bufA = agg + (size_t)NN * 256;             // 51.2 MB
  float* bufB = bufA + (size_t)NN * 256;            // 51.2 MB
  int* flag = (int*)(bufB + (size_t)NN * 256);      // 4 B

  const size_t aggBytes = (size_t)NN * 256 * sizeof(float);
  dim3 blk(256);
  dim3 gSc(NE * 64 / 256);
  dim3 gG(782, 4);
  dim3 gG2(782, 2);

  detect_kernel<<<1, 64, 0, stream>>>(feat, flag);

  // layer 0: h_in = feat (flag dtype) -> bufA
  hipMemsetAsync(agg, 0, aggBytes, stream);
  scatter_mean_kernel<<<gSc, blk, 0, stream>>>(feat, src, dst, indeg, agg, flag, 0);
  gemm_dual_kernel<256, false><<<gG, blk, 0, stream>>>(feat, agg, ws0, wn0, b0, bufA, flag, 0);
  ln_relu_kernel<<<12500, blk, 0, stream>>>(bufA, g0, be0, flag);
  // layer 1: bufA (fp32) -> bufB
  hipMemsetAsync(agg, 0, aggBytes, stream);
  scatter_mean_kernel<<<gSc, blk, 0, stream>>>(bufA, src, dst, indeg, agg, flag, 1);
  gemm_dual_kernel<256, false><<<gG, blk, 0, stream>>>(bufA, agg, ws1, wn1, b1, bufB, flag, 1);
  ln_relu_kernel<<<12500, blk, 0, stream>>>(bufB, g1, be1, flag);
  // layer 2: bufB (fp32) -> d_out (flag dtype)
  hipMemsetAsync(agg, 0, aggBytes, stream);
  scatter_mean_kernel<<<gSc, blk, 0, stream>>>(bufB, src, dst, indeg, agg, flag, 1);
  gemm_dual_kernel<128, true><<<gG2, blk, 0, stream>>>(bufB, agg, ws2, wn2, b2, d_out, flag, 1);
}

// Round 3
// 1199.078 us; speedup vs baseline: 7.1840x; 7.1840x over previous
//
#include <hip/hip_runtime.h>
#include <stdint.h>

#define NN 50000
#define NE 800000
#define LN_EPS 1e-5f

__device__ __forceinline__ float bfbits2f(unsigned short u) {
  return __uint_as_float(((unsigned)u) << 16);
}
__device__ __forceinline__ unsigned short f2bfbits(float f) {
  unsigned u = __float_as_uint(f);
  u += 0x7FFFu + ((u >> 16) & 1u);   // round-to-nearest-even
  return (unsigned short)(u >> 16);
}
__device__ __forceinline__ float4 ld4f(const void* p, size_t i, bool f32) {
  if (f32) return *reinterpret_cast<const float4*>((const float*)p + i);
  ushort4 r = *reinterpret_cast<const ushort4*>((const unsigned short*)p + i);
  return make_float4(bfbits2f(r.x), bfbits2f(r.y), bfbits2f(r.z), bfbits2f(r.w));
}
__device__ __forceinline__ float ld1f(const void* p, size_t i, bool f32) {
  return f32 ? ((const float*)p)[i] : bfbits2f(((const unsigned short*)p)[i]);
}

// fp32 vs bf16 input detection (fp32 read as bf16 halves -> huge/NaN values).
__global__ void detect_kernel(const void* feat, int* flag) {
  int cnt = 0;
  const unsigned short* u = (const unsigned short*)feat;
  for (int i = threadIdx.x; i < 512; i += 64) {
    float v = bfbits2f(u[i]);
    if (!(fabsf(v) < 1e6f)) cnt++;
  }
#pragma unroll
  for (int off = 32; off > 0; off >>= 1) cnt += __shfl_down(cnt, off, 64);
  if (threadIdx.x == 0) flag[0] = (cnt > 8) ? 1 : 0;
}

// ---- CSR build (edge list identical across layers; built once per launch) ----
__global__ void count_kernel(const int* __restrict__ dst, int* __restrict__ counts) {
  int e = blockIdx.x * blockDim.x + threadIdx.x;
  if (e >= NE) return;
  atomicAdd(&counts[dst[e]], 1);
}

__global__ __launch_bounds__(1024) void scan_kernel(const int* __restrict__ counts,
                                                    int* __restrict__ rowptr,
                                                    int* __restrict__ cursor) {
  __shared__ int part[1024];
  int tid = threadIdx.x;
  const int PER = (NN + 1023) / 1024;  // 49
  int base = tid * PER;
  int sum = 0;
  for (int i = 0; i < PER; ++i) {
    int idx = base + i;
    if (idx < NN) sum += counts[idx];
  }
  part[tid] = sum;
  __syncthreads();
  for (int off = 1; off < 1024; off <<= 1) {
    int t = (tid >= off) ? part[tid - off] : 0;
    __syncthreads();
    if (tid >= off) part[tid] += t;
    __syncthreads();
  }
  int run = part[tid] - sum;  // exclusive prefix of this thread's chunk
  for (int i = 0; i < PER; ++i) {
    int idx = base + i;
    if (idx < NN) {
      rowptr[idx] = run;
      cursor[idx] = run;
      run += counts[idx];
    }
  }
  if (tid == 0) rowptr[NN] = part[1023];
}

__global__ void fill_kernel(const int* __restrict__ src, const int* __restrict__ dst,
                            int* __restrict__ cursor, int* __restrict__ csr_src) {
  int e = blockIdx.x * blockDim.x + threadIdx.x;
  if (e >= NE) return;
  int pos = atomicAdd(&cursor[dst[e]], 1);
  csr_src[pos] = src[e];
}

// ---- mean aggregation as CSR gather: one wave per dst row, 4 feats/lane ----
__global__ __launch_bounds__(256) void gather_mean_kernel(
    const void* __restrict__ h, const int* __restrict__ rowptr,
    const int* __restrict__ csr_src, const void* __restrict__ indeg,
    float* __restrict__ agg, const int* __restrict__ dtflag, int h_always_f32) {
  bool inf32 = dtflag[0] != 0;
  bool hf32 = h_always_f32 || inf32;
  int row = blockIdx.x * 4 + (threadIdx.x >> 6);
  int lane = threadIdx.x & 63;
  int beg = rowptr[row], end = rowptr[row + 1];
  float ax = 0.f, ay = 0.f, az = 0.f, aw = 0.f;
  int i = beg;
  for (; i + 2 <= end; i += 2) {
    int s0 = csr_src[i], s1 = csr_src[i + 1];
    float4 v0 = ld4f(h, (size_t)s0 * 256 + lane * 4, hf32);
    float4 v1 = ld4f(h, (size_t)s1 * 256 + lane * 4, hf32);
    ax += v0.x + v1.x; ay += v0.y + v1.y;
    az += v0.z + v1.z; aw += v0.w + v1.w;
  }
  if (i < end) {
    int s0 = csr_src[i];
    float4 v0 = ld4f(h, (size_t)s0 * 256 + lane * 4, hf32);
    ax += v0.x; ay += v0.y; az += v0.z; aw += v0.w;
  }
  float rdeg = 1.0f / ld1f(indeg, row, inf32);
  float4 o = {ax * rdeg, ay * rdeg, az * rdeg, aw * rdeg};
  *reinterpret_cast<float4*>(agg + (size_t)row * 256 + lane * 4) = o;
}

// C = A1 @ B1 + A2(f32) @ B2 + bias.  64x64 tile, BK=16, 4x4/thread.
template <int N, bool LAST>
__global__ __launch_bounds__(256) void gemm_dual_kernel(
    const void* __restrict__ A1, const float* __restrict__ A2,
    const void* __restrict__ B1, const void* __restrict__ B2,
    const void* __restrict__ bias, void* __restrict__ out,
    const int* __restrict__ dtflag, int a1_always_f32) {
  bool inf32 = dtflag[0] != 0;
  bool a1f32 = a1_always_f32 || inf32;
  __shared__ __align__(16) float As[16][68];
  __shared__ __align__(16) float Bs[16][68];
  const int tid = threadIdx.x;
  const int row0 = blockIdx.x * 64;
  const int col0 = blockIdx.y * 64;
  const int ty = tid >> 4;
  const int tx = tid & 15;
  const int lm = tid >> 2;
  const int lk = (tid & 3) * 4;
  const int bk = tid >> 4;
  const int bn = (tid & 15) * 4;

  float acc[4][4] = {};
  for (int phase = 0; phase < 2; ++phase) {
    const void* Bp = phase ? B2 : B1;
    for (int kb = 0; kb < 256; kb += 16) {
      int grow = row0 + lm;
      float4 a = make_float4(0.f, 0.f, 0.f, 0.f);
      if (grow < NN) {
        if (phase == 0)
          a = ld4f(A1, (size_t)grow * 256 + kb + lk, a1f32);
        else
          a = *reinterpret_cast<const float4*>(A2 + (size_t)grow * 256 + kb + lk);
      }
      As[lk + 0][lm] = a.x; As[lk + 1][lm] = a.y;
      As[lk + 2][lm] = a.z; As[lk + 3][lm] = a.w;
      float4 b = ld4f(Bp, (size_t)(kb + bk) * N + col0 + bn, inf32);
      Bs[bk][bn + 0] = b.x; Bs[bk][bn + 1] = b.y;
      Bs[bk][bn + 2] = b.z; Bs[bk][bn + 3] = b.w;
      __syncthreads();
#pragma unroll
      for (int k = 0; k < 16; ++k) {
        float4 av = *reinterpret_cast<const float4*>(&As[k][ty * 4]);
        float4 bv = *reinterpret_cast<const float4*>(&Bs[k][tx * 4]);
        float aa[4] = {av.x, av.y, av.z, av.w};
        float bb[4] = {bv.x, bv.y, bv.z, bv.w};
#pragma unroll
        for (int i = 0; i < 4; ++i)
#pragma unroll
          for (int j = 0; j < 4; ++j) acc[i][j] += aa[i] * bb[j];
      }
      __syncthreads();
    }
  }
  float bc[4];
#pragma unroll
  for (int j = 0; j < 4; ++j) bc[j] = ld1f(bias, col0 + tx * 4 + j, inf32);
#pragma unroll
  for (int i = 0; i < 4; ++i) {
    int r = row0 + ty * 4 + i;
    if (r >= NN) break;
    float o0 = acc[i][0] + bc[0], o1 = acc[i][1] + bc[1];
    float o2 = acc[i][2] + bc[2], o3 = acc[i][3] + bc[3];
    size_t idx = (size_t)r * N + col0 + tx * 4;
    if (LAST && !inf32) {
      ushort4 v = {f2bfbits(o0), f2bfbits(o1), f2bfbits(o2), f2bfbits(o3)};
      *reinterpret_cast<ushort4*>((unsigned short*)out + idx) = v;
    } else {
      float4 v = {o0, o1, o2, o3};
      *reinterpret_cast<float4*>((float*)out + idx) = v;
    }
  }
}

// In-place LN over 256 cols + ReLU on fp32 buffer. One wave per row.
__global__ void ln_relu_kernel(float* __restrict__ buf,
                               const void* __restrict__ g,
                               const void* __restrict__ be,
                               const int* __restrict__ dtflag) {
  bool inf32 = dtflag[0] != 0;
  int row = blockIdx.x * 4 + (threadIdx.x >> 6);
  int lane = threadIdx.x & 63;
  float* p = buf + (size_t)row * 256 + lane * 4;
  float4 v = *reinterpret_cast<const float4*>(p);
  float s = v.x + v.y + v.z + v.w;
  float sq = v.x * v.x + v.y * v.y + v.z * v.z + v.w * v.w;
#pragma unroll
  for (int off = 32; off > 0; off >>= 1) {
    s += __shfl_down(s, off, 64);
    sq += __shfl_down(sq, off, 64);
  }
  s = __shfl(s, 0, 64);
  sq = __shfl(sq, 0, 64);
  float mu = s * (1.0f / 256.0f);
  float var = fmaxf(sq * (1.0f / 256.0f) - mu * mu, 0.0f);
  float rs = rsqrtf(var + LN_EPS);
  float vv[4] = {v.x, v.y, v.z, v.w};
  float4 o;
#pragma unroll
  for (int i = 0; i < 4; ++i) {
    int c = lane * 4 + i;
    float x = (vv[i] - mu) * rs * ld1f(g, c, inf32) + ld1f(be, c, inf32);
    (&o.x)[i] = fmaxf(x, 0.0f);
  }
  *reinterpret_cast<float4*>(p) = o;
}

extern "C" void kernel_launch(void* const* d_in, const int* in_sizes, int n_in,
                              void* d_out, int out_size, void* d_ws, size_t ws_size,
                              hipStream_t stream) {
  const void* feat = d_in[0];
  const int* ei = (const int*)d_in[1];
  const void* indeg = d_in[2];
  const void* ws0 = d_in[3]; const void* wn0 = d_in[4]; const void* b0 = d_in[5];
  const void* ws1 = d_in[6]; const void* wn1 = d_in[7]; const void* b1 = d_in[8];
  const void* ws2 = d_in[9]; const void* wn2 = d_in[10]; const void* b2 = d_in[11];
  const void* g0 = d_in[12]; const void* be0 = d_in[13];
  const void* g1 = d_in[14]; const void* be1 = d_in[15];
  const int* src = ei;
  const int* dst = ei + NE;

  float* agg = (float*)d_ws;                        // 51.2 MB
  float* bufA = agg + (size_t)NN * 256;             // 51.2 MB
  float* bufB = bufA + (size_t)NN * 256;            // 51.2 MB
  int* flag = (int*)(bufB + (size_t)NN * 256);      // 4 B

  // CSR scratch lives in d_out (3.8 MB of 25.6 MB); last CSR use (layer-2
  // gather) precedes the final GEMM's overwrite of d_out.
  int* counts = (int*)d_out;            // NN
  int* rowptr = counts + NN;            // NN+1
  int* cursor = rowptr + NN + 1;        // NN
  int* csr_src = cursor + NN;           // NE

  dim3 blk(256);
  dim3 gE((NE + 255) / 256);
  dim3 gRow(12500);
  dim3 gG(782, 4);
  dim3 gG2(782, 2);

  detect_kernel<<<1, 64, 0, stream>>>(feat, flag);

  // CSR build (once; same edges all layers)
  hipMemsetAsync(counts, 0, NN * sizeof(int), stream);
  count_kernel<<<gE, blk, 0, stream>>>(dst, counts);
  scan_kernel<<<1, 1024, 0, stream>>>(counts, rowptr, cursor);
  fill_kernel<<<gE, blk, 0, stream>>>(src, dst, cursor, csr_src);

  // layer 0: feat (flag dtype) -> bufA
  gather_mean_kernel<<<gRow, blk, 0, stream>>>(feat, rowptr, csr_src, indeg, agg, flag, 0);
  gemm_dual_kernel<256, false><<<gG, blk, 0, stream>>>(feat, agg, ws0, wn0, b0, bufA, flag, 0);
  ln_relu_kernel<<<gRow, blk, 0, stream>>>(bufA, g0, be0, flag);
  // layer 1: bufA (fp32) -> bufB
  gather_mean_kernel<<<gRow, blk, 0, stream>>>(bufA, rowptr, csr_src, indeg, agg, flag, 1);
  gemm_dual_kernel<256, false><<<gG, blk, 0, stream>>>(bufA, agg, ws1, wn1, b1, bufB, flag, 1);
  ln_relu_kernel<<<gRow, blk, 0, stream>>>(bufB, g1, be1, flag);
  // layer 2: bufB (fp32) -> d_out (fp32), overwrites CSR scratch
  gather_mean_kernel<<<gRow, blk, 0, stream>>>(bufB, rowptr, csr_src, indeg, agg, flag, 1);
  gemm_dual_kernel<128, true><<<gG2, blk, 0, stream>>>(bufB, agg, ws2, wn2, b2, d_out, flag, 1);
}

// Round 4
// 698.783 us; speedup vs baseline: 12.3275x; 1.7160x over previous
//
#include <hip/hip_runtime.h>
#include <stdint.h>

#define NN 50000
#define NE 800000
#define LN_EPS 1e-5f

typedef __attribute__((ext_vector_type(8))) __bf16 bf16x8;
typedef __attribute__((ext_vector_type(4))) float floatx4;

__device__ __forceinline__ float bfbits2f(unsigned short u) {
  return __uint_as_float(((unsigned)u) << 16);
}
__device__ __forceinline__ unsigned short f2bfbits(float f) {
  unsigned u = __float_as_uint(f);
  u += 0x7FFFu + ((u >> 16) & 1u);   // round-to-nearest-even
  return (unsigned short)(u >> 16);
}
__device__ __forceinline__ float4 ld4f(const void* p, size_t i, bool f32) {
  if (f32) return *reinterpret_cast<const float4*>((const float*)p + i);
  ushort4 r = *reinterpret_cast<const ushort4*>((const unsigned short*)p + i);
  return make_float4(bfbits2f(r.x), bfbits2f(r.y), bfbits2f(r.z), bfbits2f(r.w));
}
__device__ __forceinline__ float ld1f(const void* p, size_t i, bool f32) {
  return f32 ? ((const float*)p)[i] : bfbits2f(((const unsigned short*)p)[i]);
}

// fp32 vs bf16 input detection (fp32 read as bf16 halves -> huge/NaN values).
__global__ void detect_kernel(const void* feat, int* flag) {
  int cnt = 0;
  const unsigned short* u = (const unsigned short*)feat;
  for (int i = threadIdx.x; i < 512; i += 64) {
    float v = bfbits2f(u[i]);
    if (!(fabsf(v) < 1e6f)) cnt++;
  }
#pragma unroll
  for (int off = 32; off > 0; off >>= 1) cnt += __shfl_down(cnt, off, 64);
  if (threadIdx.x == 0) flag[0] = (cnt > 8) ? 1 : 0;
}

// feat (flag dtype) -> bf16
__global__ void conv_feat_kernel(const void* __restrict__ feat,
                                 unsigned short* __restrict__ featbf,
                                 const int* __restrict__ flag) {
  bool f32 = flag[0] != 0;
  size_t i = ((size_t)blockIdx.x * blockDim.x + threadIdx.x) * 4;
  float4 v = ld4f(feat, i, f32);
  ushort4 o = {f2bfbits(v.x), f2bfbits(v.y), f2bfbits(v.z), f2bfbits(v.w)};
  *reinterpret_cast<ushort4*>(featbf + i) = o;
}

// Bt[n][k] bf16, K=512 packed [Wself; Wneigh], n-major for MFMA B-frag reads.
template <int N>
__global__ void conv_w_kernel(const void* __restrict__ wself,
                              const void* __restrict__ wneigh,
                              unsigned short* __restrict__ Bt,
                              const int* __restrict__ flag) {
  bool f32 = flag[0] != 0;
  int t = blockIdx.x * blockDim.x + threadIdx.x;  // N*512
  int k = t & 511, n = t >> 9;
  float v = (k < 256) ? ld1f(wself, (size_t)k * N + n, f32)
                      : ld1f(wneigh, (size_t)(k - 256) * N + n, f32);
  Bt[t] = f2bfbits(v);
}

// ---- CSR build ----
__global__ void count_kernel(const int* __restrict__ dst, int* __restrict__ counts) {
  int e = blockIdx.x * blockDim.x + threadIdx.x;
  if (e >= NE) return;
  atomicAdd(&counts[dst[e]], 1);
}

__global__ __launch_bounds__(1024) void scan_kernel(const int* __restrict__ counts,
                                                    int* __restrict__ rowptr,
                                                    int* __restrict__ cursor) {
  __shared__ int part[1024];
  int tid = threadIdx.x;
  const int PER = (NN + 1023) / 1024;
  int base = tid * PER;
  int sum = 0;
  for (int i = 0; i < PER; ++i) {
    int idx = base + i;
    if (idx < NN) sum += counts[idx];
  }
  part[tid] = sum;
  __syncthreads();
  for (int off = 1; off < 1024; off <<= 1) {
    int t = (tid >= off) ? part[tid - off] : 0;
    __syncthreads();
    if (tid >= off) part[tid] += t;
    __syncthreads();
  }
  int run = part[tid] - sum;
  for (int i = 0; i < PER; ++i) {
    int idx = base + i;
    if (idx < NN) {
      rowptr[idx] = run;
      cursor[idx] = run;
      run += counts[idx];
    }
  }
  if (tid == 0) rowptr[NN] = part[1023];
}

__global__ void fill_kernel(const int* __restrict__ src, const int* __restrict__ dst,
                            int* __restrict__ cursor, int* __restrict__ csr_src) {
  int e = blockIdx.x * blockDim.x + threadIdx.x;
  if (e >= NE) return;
  int pos = atomicAdd(&cursor[dst[e]], 1);
  csr_src[pos] = src[e];
}

// ---- mean aggregation: one wave per dst row over bf16 h, bf16 out ----
__global__ __launch_bounds__(256) void gather_mean_kernel(
    const unsigned short* __restrict__ h, const int* __restrict__ rowptr,
    const int* __restrict__ csr_src, const void* __restrict__ indeg,
    unsigned short* __restrict__ agg, const int* __restrict__ dtflag) {
  bool inf32 = dtflag[0] != 0;
  int row = blockIdx.x * 4 + (threadIdx.x >> 6);
  int lane = threadIdx.x & 63;
  int beg = rowptr[row], end = rowptr[row + 1];
  float ax = 0.f, ay = 0.f, az = 0.f, aw = 0.f;
  int i = beg;
  for (; i + 2 <= end; i += 2) {
    int s0 = csr_src[i], s1 = csr_src[i + 1];
    ushort4 r0 = *reinterpret_cast<const ushort4*>(h + (size_t)s0 * 256 + lane * 4);
    ushort4 r1 = *reinterpret_cast<const ushort4*>(h + (size_t)s1 * 256 + lane * 4);
    ax += bfbits2f(r0.x) + bfbits2f(r1.x);
    ay += bfbits2f(r0.y) + bfbits2f(r1.y);
    az += bfbits2f(r0.z) + bfbits2f(r1.z);
    aw += bfbits2f(r0.w) + bfbits2f(r1.w);
  }
  if (i < end) {
    int s0 = csr_src[i];
    ushort4 r0 = *reinterpret_cast<const ushort4*>(h + (size_t)s0 * 256 + lane * 4);
    ax += bfbits2f(r0.x); ay += bfbits2f(r0.y);
    az += bfbits2f(r0.z); aw += bfbits2f(r0.w);
  }
  float rd = 1.0f / ld1f(indeg, row, inf32);
  ushort4 o = {f2bfbits(ax * rd), f2bfbits(ay * rd), f2bfbits(az * rd), f2bfbits(aw * rd)};
  *reinterpret_cast<ushort4*>(agg + (size_t)row * 256 + lane * 4) = o;
}

// ---- MFMA GEMM: C = [A1|A2](bf16, K=512) @ Bt^T + bias ----
// 128x128 tile, BK=32, 4 waves, each wave 4x4 of 16x16x32 MFMA tiles.
template <int N, bool LAST>
__global__ __launch_bounds__(256) void gemm_mfma_kernel(
    const unsigned short* __restrict__ A1, const unsigned short* __restrict__ A2,
    const unsigned short* __restrict__ Bt, const void* __restrict__ bias,
    void* __restrict__ out, const int* __restrict__ dtflag) {
  constexpr int LDA = 40;  // bf16 elems per LDS row (32 + 8 pad, keeps 16B align)
  __shared__ unsigned short As[128 * LDA];
  __shared__ unsigned short Bs[128 * LDA];
  const int tid = threadIdx.x;
  const int lane = tid & 63;
  const int wave = tid >> 6;
  const int row0 = blockIdx.x * 128;
  const int col0 = blockIdx.y * 128;
  const int wr = (wave >> 1) * 64;
  const int wc = (wave & 1) * 64;
  const int fr = lane & 15;
  const int fh = (lane >> 4) * 8;

  floatx4 acc[4][4];
#pragma unroll
  for (int i = 0; i < 4; ++i)
#pragma unroll
    for (int j = 0; j < 4; ++j) acc[i][j] = (floatx4){0.f, 0.f, 0.f, 0.f};

  // staging: 512 chunks of 16B per tile, 2 chunks/thread
  const int r0 = tid >> 2;                 // chunk tid: rows 0..63
  const int r1 = (tid + 256) >> 2;         // rows 64..127
  const int oo = (tid & 3) * 8;            // bf16 offset within 32-k row

  for (int kb = 0; kb < 512; kb += 32) {
    const unsigned short* Ap = (kb < 256) ? A1 : A2;
    const int kc = kb & 255;
    // rows past NN read garbage inside ws (safe; outputs guarded)
    uint4 a0 = *reinterpret_cast<const uint4*>(Ap + (size_t)(row0 + r0) * 256 + kc + oo);
    uint4 a1 = *reinterpret_cast<const uint4*>(Ap + (size_t)(row0 + r1) * 256 + kc + oo);
    uint4 b0 = *reinterpret_cast<const uint4*>(Bt + (size_t)(col0 + r0) * 512 + kb + oo);
    uint4 b1 = *reinterpret_cast<const uint4*>(Bt + (size_t)(col0 + r1) * 512 + kb + oo);
    if (kb) __syncthreads();
    *reinterpret_cast<uint4*>(As + r0 * LDA + oo) = a0;
    *reinterpret_cast<uint4*>(As + r1 * LDA + oo) = a1;
    *reinterpret_cast<uint4*>(Bs + r0 * LDA + oo) = b0;
    *reinterpret_cast<uint4*>(Bs + r1 * LDA + oo) = b1;
    __syncthreads();
    bf16x8 af[4], bfr[4];
#pragma unroll
    for (int i = 0; i < 4; ++i)
      af[i] = *reinterpret_cast<const bf16x8*>(As + (wr + i * 16 + fr) * LDA + fh);
#pragma unroll
    for (int j = 0; j < 4; ++j)
      bfr[j] = *reinterpret_cast<const bf16x8*>(Bs + (wc + j * 16 + fr) * LDA + fh);
#pragma unroll
    for (int i = 0; i < 4; ++i)
#pragma unroll
      for (int j = 0; j < 4; ++j)
        acc[i][j] = __builtin_amdgcn_mfma_f32_16x16x32_bf16(af[i], bfr[j], acc[i][j], 0, 0, 0);
  }

  bool inf32 = dtflag[0] != 0;
#pragma unroll
  for (int j = 0; j < 4; ++j) {
    int gc = col0 + wc + j * 16 + fr;
    float bj = ld1f(bias, gc, inf32);
#pragma unroll
    for (int i = 0; i < 4; ++i) {
      int rbase = row0 + wr + i * 16 + (lane >> 4) * 4;
#pragma unroll
      for (int r = 0; r < 4; ++r) {
        int gr = rbase + r;
        if (gr < NN) {
          float v = acc[i][j][r] + bj;
          if (LAST && !inf32)
            ((unsigned short*)out)[(size_t)gr * N + gc] = f2bfbits(v);
          else
            ((float*)out)[(size_t)gr * N + gc] = v;
        }
      }
    }
  }
}

// LN over 256 cols + ReLU: fp32 in, bf16 out. One wave per row.
__global__ void ln_relu_kernel(const float* __restrict__ pre,
                               unsigned short* __restrict__ hbf,
                               const void* __restrict__ g,
                               const void* __restrict__ be,
                               const int* __restrict__ dtflag) {
  bool inf32 = dtflag[0] != 0;
  int row = blockIdx.x * 4 + (threadIdx.x >> 6);
  int lane = threadIdx.x & 63;
  float4 v = *reinterpret_cast<const float4*>(pre + (size_t)row * 256 + lane * 4);
  float s = v.x + v.y + v.z + v.w;
  float sq = v.x * v.x + v.y * v.y + v.z * v.z + v.w * v.w;
#pragma unroll
  for (int off = 32; off > 0; off >>= 1) {
    s += __shfl_down(s, off, 64);
    sq += __shfl_down(sq, off, 64);
  }
  s = __shfl(s, 0, 64);
  sq = __shfl(sq, 0, 64);
  float mu = s * (1.0f / 256.0f);
  float var = fmaxf(sq * (1.0f / 256.0f) - mu * mu, 0.0f);
  float rs = rsqrtf(var + LN_EPS);
  float vv[4] = {v.x, v.y, v.z, v.w};
  ushort4 o;
#pragma unroll
  for (int i = 0; i < 4; ++i) {
    int c = lane * 4 + i;
    float x = (vv[i] - mu) * rs * ld1f(g, c, inf32) + ld1f(be, c, inf32);
    (&o.x)[i] = f2bfbits(fmaxf(x, 0.0f));
  }
  *reinterpret_cast<ushort4*>(hbf + (size_t)row * 256 + lane * 4) = o;
}

extern "C" void kernel_launch(void* const* d_in, const int* in_sizes, int n_in,
                              void* d_out, int out_size, void* d_ws, size_t ws_size,
                              hipStream_t stream) {
  const void* feat = d_in[0];
  const int* ei = (const int*)d_in[1];
  const void* indeg = d_in[2];
  const void* ws0 = d_in[3]; const void* wn0 = d_in[4]; const void* b0 = d_in[5];
  const void* ws1 = d_in[6]; const void* wn1 = d_in[7]; const void* b1 = d_in[8];
  const void* ws2 = d_in[9]; const void* wn2 = d_in[10]; const void* b2 = d_in[11];
  const void* g0 = d_in[12]; const void* be0 = d_in[13];
  const void* g1 = d_in[14]; const void* be1 = d_in[15];
  const int* src = ei;
  const int* dst = ei + NE;

  unsigned short* featbf = (unsigned short*)d_ws;                 // 25.6 MB
  unsigned short* aggbf  = featbf + (size_t)NN * 256;             // 25.6 MB
  unsigned short* hbf    = aggbf + (size_t)NN * 256;              // 25.6 MB
  float* pre = (float*)(hbf + (size_t)NN * 256);                  // 51.2 MB
  unsigned short* Bt0 = (unsigned short*)(pre + (size_t)NN * 256);
  unsigned short* Bt1 = Bt0 + 256 * 512;
  unsigned short* Bt2 = Bt1 + 256 * 512;
  int* flag = (int*)(Bt2 + 128 * 512);

  // CSR scratch in d_out (3.8 MB of 25.6 MB); last use precedes final GEMM.
  int* counts = (int*)d_out;
  int* rowptr = counts + NN;
  int* cursor = rowptr + NN + 1;
  int* csr_src = cursor + NN;

  dim3 blk(256);
  dim3 gE((NE + 255) / 256);
  dim3 gRow(12500);
  dim3 gG(391, 2);
  dim3 gG2(391, 1);

  detect_kernel<<<1, 64, 0, stream>>>(feat, flag);
  conv_feat_kernel<<<12500, blk, 0, stream>>>(feat, featbf, flag);
  conv_w_kernel<256><<<512, blk, 0, stream>>>(ws0, wn0, Bt0, flag);
  conv_w_kernel<256><<<512, blk, 0, stream>>>(ws1, wn1, Bt1, flag);
  conv_w_kernel<128><<<256, blk, 0, stream>>>(ws2, wn2, Bt2, flag);

  hipMemsetAsync(counts, 0, NN * sizeof(int), stream);
  count_kernel<<<gE, blk, 0, stream>>>(dst, counts);
  scan_kernel<<<1, 1024, 0, stream>>>(counts, rowptr, cursor);
  fill_kernel<<<gE, blk, 0, stream>>>(src, dst, cursor, csr_src);

  // layer 0
  gather_mean_kernel<<<gRow, blk, 0, stream>>>(featbf, rowptr, csr_src, indeg, aggbf, flag);
  gemm_mfma_kernel<256, false><<<gG, blk, 0, stream>>>(featbf, aggbf, Bt0, b0, pre, flag);
  ln_relu_kernel<<<gRow, blk, 0, stream>>>(pre, hbf, g0, be0, flag);
  // layer 1
  gather_mean_kernel<<<gRow, blk, 0, stream>>>(hbf, rowptr, csr_src, indeg, aggbf, flag);
  gemm_mfma_kernel<256, false><<<gG, blk, 0, stream>>>(hbf, aggbf, Bt1, b1, pre, flag);
  ln_relu_kernel<<<gRow, blk, 0, stream>>>(pre, hbf, g1, be1, flag);
  // layer 2 (no LN/ReLU) -> d_out
  gather_mean_kernel<<<gRow, blk, 0, stream>>>(hbf, rowptr, csr_src, indeg, aggbf, flag);
  gemm_mfma_kernel<128, true><<<gG2, blk, 0, stream>>>(hbf, aggbf, Bt2, b2, d_out, flag);
}

// Round 5
// 559.453 us; speedup vs baseline: 15.3976x; 1.2490x over previous
//
#include <hip/hip_runtime.h>
#include <stdint.h>

#define NN 50000
#define NE 800000
#define LN_EPS 1e-5f
#define NBLK 196  // ceil(NN/256)

typedef __attribute__((ext_vector_type(8))) __bf16 bf16x8;
typedef __attribute__((ext_vector_type(4))) float floatx4;

__device__ __forceinline__ float bfbits2f(unsigned short u) {
  return __uint_as_float(((unsigned)u) << 16);
}
__device__ __forceinline__ unsigned short f2bfbits(float f) {
  unsigned u = __float_as_uint(f);
  u += 0x7FFFu + ((u >> 16) & 1u);   // round-to-nearest-even
  return (unsigned short)(u >> 16);
}
__device__ __forceinline__ float4 ld4f(const void* p, size_t i, bool f32) {
  if (f32) return *reinterpret_cast<const float4*>((const float*)p + i);
  ushort4 r = *reinterpret_cast<const ushort4*>((const unsigned short*)p + i);
  return make_float4(bfbits2f(r.x), bfbits2f(r.y), bfbits2f(r.z), bfbits2f(r.w));
}
__device__ __forceinline__ float ld1f(const void* p, size_t i, bool f32) {
  return f32 ? ((const float*)p)[i] : bfbits2f(((const unsigned short*)p)[i]);
}

// fp32 vs bf16 input detection (fp32 read as bf16 halves -> huge/NaN values).
__global__ void detect_kernel(const void* feat, int* flag) {
  int cnt = 0;
  const unsigned short* u = (const unsigned short*)feat;
  for (int i = threadIdx.x; i < 512; i += 64) {
    float v = bfbits2f(u[i]);
    if (!(fabsf(v) < 1e6f)) cnt++;
  }
#pragma unroll
  for (int off = 32; off > 0; off >>= 1) cnt += __shfl_down(cnt, off, 64);
  if (threadIdx.x == 0) flag[0] = (cnt > 8) ? 1 : 0;
}

__global__ void conv_feat_kernel(const void* __restrict__ feat,
                                 unsigned short* __restrict__ featbf,
                                 const int* __restrict__ flag) {
  bool f32 = flag[0] != 0;
  size_t i = ((size_t)blockIdx.x * blockDim.x + threadIdx.x) * 4;
  float4 v = ld4f(feat, i, f32);
  ushort4 o = {f2bfbits(v.x), f2bfbits(v.y), f2bfbits(v.z), f2bfbits(v.w)};
  *reinterpret_cast<ushort4*>(featbf + i) = o;
}

// Bt[n][k] bf16, K=512 packed [Wself; Wneigh], n-major for MFMA B-frag reads.
template <int N>
__global__ void conv_w_kernel(const void* __restrict__ wself,
                              const void* __restrict__ wneigh,
                              unsigned short* __restrict__ Bt,
                              const int* __restrict__ flag) {
  bool f32 = flag[0] != 0;
  int t = blockIdx.x * blockDim.x + threadIdx.x;  // N*512
  int k = t & 511, n = t >> 9;
  float v = (k < 256) ? ld1f(wself, (size_t)k * N + n, f32)
                      : ld1f(wneigh, (size_t)(k - 256) * N + n, f32);
  Bt[t] = f2bfbits(v);
}

// ---- CSR build: count -> hierarchical scan (3 kernels) -> fill ----
__global__ void count_kernel(const int* __restrict__ dst, int* __restrict__ counts) {
  int e = blockIdx.x * blockDim.x + threadIdx.x;
  if (e >= NE) return;
  atomicAdd(&counts[dst[e]], 1);
}

__global__ __launch_bounds__(256) void bsum_kernel(const int* __restrict__ counts,
                                                   int* __restrict__ bsum) {
  int i = blockIdx.x * 256 + threadIdx.x;
  int v = (i < NN) ? counts[i] : 0;
#pragma unroll
  for (int off = 32; off > 0; off >>= 1) v += __shfl_down(v, off, 64);
  __shared__ int w[4];
  if ((threadIdx.x & 63) == 0) w[threadIdx.x >> 6] = v;
  __syncthreads();
  if (threadIdx.x == 0) bsum[blockIdx.x] = w[0] + w[1] + w[2] + w[3];
}

__global__ __launch_bounds__(256) void bscan_kernel(const int* __restrict__ bsum,
                                                    int* __restrict__ boff) {
  __shared__ int sh[256];
  int tid = threadIdx.x;
  int v = (tid < NBLK) ? bsum[tid] : 0;
  sh[tid] = v;
  __syncthreads();
  for (int off = 1; off < 256; off <<= 1) {
    int t = (tid >= off) ? sh[tid - off] : 0;
    __syncthreads();
    sh[tid] += t;
    __syncthreads();
  }
  boff[tid] = sh[tid] - v;  // exclusive prefix
}

__global__ __launch_bounds__(256) void rowptr_kernel(const int* __restrict__ counts,
                                                     const int* __restrict__ boff,
                                                     int* __restrict__ rowptr,
                                                     int* __restrict__ cursor) {
  __shared__ int sh[256];
  int tid = threadIdx.x;
  int i = blockIdx.x * 256 + tid;
  int v = (i < NN) ? counts[i] : 0;
  sh[tid] = v;
  __syncthreads();
  for (int off = 1; off < 256; off <<= 1) {
    int t = (tid >= off) ? sh[tid - off] : 0;
    __syncthreads();
    sh[tid] += t;
    __syncthreads();
  }
  int incl = sh[tid];
  int base = boff[blockIdx.x];
  if (i < NN) {
    int r = base + incl - v;
    rowptr[i] = r;
    cursor[i] = r;
  }
  if (i == NN - 1) rowptr[NN] = base + incl;
}

__global__ void fill_kernel(const int* __restrict__ src, const int* __restrict__ dst,
                            int* __restrict__ cursor, int* __restrict__ csr_src) {
  int e = blockIdx.x * blockDim.x + threadIdx.x;
  if (e >= NE) return;
  int pos = atomicAdd(&cursor[dst[e]], 1);
  csr_src[pos] = src[e];
}

// ---- mean aggregation: one wave per dst row, 2 edges per wave-step,
//      16B per lane (lanes 0-31 edge e, lanes 32-63 edge e+1) ----
__global__ __launch_bounds__(256) void gather_mean_kernel(
    const unsigned short* __restrict__ h, const int* __restrict__ rowptr,
    const int* __restrict__ csr_src, const void* __restrict__ indeg,
    unsigned short* __restrict__ agg, const int* __restrict__ dtflag) {
  bool inf32 = dtflag[0] != 0;
  int row = blockIdx.x * 4 + (threadIdx.x >> 6);
  int lane = threadIdx.x & 63;
  int half = lane >> 5;
  int l32 = lane & 31;
  int beg = rowptr[row], end = rowptr[row + 1];
  float a[8] = {};
  int e = beg + half;
  for (; e + 2 < end; e += 4) {
    int s0 = csr_src[e], s1 = csr_src[e + 2];
    uint4 r0 = *reinterpret_cast<const uint4*>(h + (size_t)s0 * 256 + l32 * 8);
    uint4 r1 = *reinterpret_cast<const uint4*>(h + (size_t)s1 * 256 + l32 * 8);
    const unsigned* u0 = &r0.x;
    const unsigned* u1 = &r1.x;
#pragma unroll
    for (int k = 0; k < 4; ++k) {
      a[2 * k] += bfbits2f((unsigned short)(u0[k] & 0xffff)) +
                  bfbits2f((unsigned short)(u1[k] & 0xffff));
      a[2 * k + 1] += bfbits2f((unsigned short)(u0[k] >> 16)) +
                      bfbits2f((unsigned short)(u1[k] >> 16));
    }
  }
  if (e < end) {
    int s0 = csr_src[e];
    uint4 r0 = *reinterpret_cast<const uint4*>(h + (size_t)s0 * 256 + l32 * 8);
    const unsigned* u0 = &r0.x;
#pragma unroll
    for (int k = 0; k < 4; ++k) {
      a[2 * k] += bfbits2f((unsigned short)(u0[k] & 0xffff));
      a[2 * k + 1] += bfbits2f((unsigned short)(u0[k] >> 16));
    }
  }
#pragma unroll
  for (int k = 0; k < 8; ++k) a[k] += __shfl_xor(a[k], 32, 64);
  if (half == 0) {
    float rd = 1.0f / ld1f(indeg, row, inf32);
    uint4 o;
    unsigned* ou = &o.x;
#pragma unroll
    for (int k = 0; k < 4; ++k) {
      unsigned lo = f2bfbits(a[2 * k] * rd);
      unsigned hi = f2bfbits(a[2 * k + 1] * rd);
      ou[k] = lo | (hi << 16);
    }
    *reinterpret_cast<uint4*>(agg + (size_t)row * 256 + l32 * 8) = o;
  }
}

// ---- MFMA GEMM: C = [A1|A2](bf16, K=512) @ Bt^T + bias ----
template <int N, bool LAST>
__global__ __launch_bounds__(256) void gemm_mfma_kernel(
    const unsigned short* __restrict__ A1, const unsigned short* __restrict__ A2,
    const unsigned short* __restrict__ Bt, const void* __restrict__ bias,
    void* __restrict__ out, const int* __restrict__ dtflag) {
  constexpr int LDA = 40;
  __shared__ unsigned short As[128 * LDA];
  __shared__ unsigned short Bs[128 * LDA];
  const int tid = threadIdx.x;
  const int lane = tid & 63;
  const int wave = tid >> 6;
  const int row0 = blockIdx.x * 128;
  const int col0 = blockIdx.y * 128;
  const int wr = (wave >> 1) * 64;
  const int wc = (wave & 1) * 64;
  const int fr = lane & 15;
  const int fh = (lane >> 4) * 8;

  floatx4 acc[4][4];
#pragma unroll
  for (int i = 0; i < 4; ++i)
#pragma unroll
    for (int j = 0; j < 4; ++j) acc[i][j] = (floatx4){0.f, 0.f, 0.f, 0.f};

  const int r0 = tid >> 2;
  const int r1 = (tid + 256) >> 2;
  const int oo = (tid & 3) * 8;

  for (int kb = 0; kb < 512; kb += 32) {
    const unsigned short* Ap = (kb < 256) ? A1 : A2;
    const int kc = kb & 255;
    uint4 a0 = *reinterpret_cast<const uint4*>(Ap + (size_t)(row0 + r0) * 256 + kc + oo);
    uint4 a1 = *reinterpret_cast<const uint4*>(Ap + (size_t)(row0 + r1) * 256 + kc + oo);
    uint4 b0 = *reinterpret_cast<const uint4*>(Bt + (size_t)(col0 + r0) * 512 + kb + oo);
    uint4 b1 = *reinterpret_cast<const uint4*>(Bt + (size_t)(col0 + r1) * 512 + kb + oo);
    if (kb) __syncthreads();
    *reinterpret_cast<uint4*>(As + r0 * LDA + oo) = a0;
    *reinterpret_cast<uint4*>(As + r1 * LDA + oo) = a1;
    *reinterpret_cast<uint4*>(Bs + r0 * LDA + oo) = b0;
    *reinterpret_cast<uint4*>(Bs + r1 * LDA + oo) = b1;
    __syncthreads();
    bf16x8 af[4], bfr[4];
#pragma unroll
    for (int i = 0; i < 4; ++i)
      af[i] = *reinterpret_cast<const bf16x8*>(As + (wr + i * 16 + fr) * LDA + fh);
#pragma unroll
    for (int j = 0; j < 4; ++j)
      bfr[j] = *reinterpret_cast<const bf16x8*>(Bs + (wc + j * 16 + fr) * LDA + fh);
#pragma unroll
    for (int i = 0; i < 4; ++i)
#pragma unroll
      for (int j = 0; j < 4; ++j)
        acc[i][j] = __builtin_amdgcn_mfma_f32_16x16x32_bf16(af[i], bfr[j], acc[i][j], 0, 0, 0);
  }

  bool inf32 = dtflag[0] != 0;
#pragma unroll
  for (int j = 0; j < 4; ++j) {
    int gc = col0 + wc + j * 16 + fr;
    float bj = ld1f(bias, gc, inf32);
#pragma unroll
    for (int i = 0; i < 4; ++i) {
      int rbase = row0 + wr + i * 16 + (lane >> 4) * 4;
#pragma unroll
      for (int r = 0; r < 4; ++r) {
        int gr = rbase + r;
        if (gr < NN) {
          float v = acc[i][j][r] + bj;
          if (LAST && !inf32)
            ((unsigned short*)out)[(size_t)gr * N + gc] = f2bfbits(v);
          else
            ((float*)out)[(size_t)gr * N + gc] = v;
        }
      }
    }
  }
}

// LN over 256 cols + ReLU: fp32 in, bf16 out. One wave per row.
__global__ void ln_relu_kernel(const float* __restrict__ pre,
                               unsigned short* __restrict__ hbf,
                               const void* __restrict__ g,
                               const void* __restrict__ be,
                               const int* __restrict__ dtflag) {
  bool inf32 = dtflag[0] != 0;
  int row = blockIdx.x * 4 + (threadIdx.x >> 6);
  int lane = threadIdx.x & 63;
  float4 v = *reinterpret_cast<const float4*>(pre + (size_t)row * 256 + lane * 4);
  float s = v.x + v.y + v.z + v.w;
  float sq = v.x * v.x + v.y * v.y + v.z * v.z + v.w * v.w;
#pragma unroll
  for (int off = 32; off > 0; off >>= 1) {
    s += __shfl_down(s, off, 64);
    sq += __shfl_down(sq, off, 64);
  }
  s = __shfl(s, 0, 64);
  sq = __shfl(sq, 0, 64);
  float mu = s * (1.0f / 256.0f);
  float var = fmaxf(sq * (1.0f / 256.0f) - mu * mu, 0.0f);
  float rs = rsqrtf(var + LN_EPS);
  float vv[4] = {v.x, v.y, v.z, v.w};
  ushort4 o;
#pragma unroll
  for (int i = 0; i < 4; ++i) {
    int c = lane * 4 + i;
    float x = (vv[i] - mu) * rs * ld1f(g, c, inf32) + ld1f(be, c, inf32);
    (&o.x)[i] = f2bfbits(fmaxf(x, 0.0f));
  }
  *reinterpret_cast<ushort4*>(hbf + (size_t)row * 256 + lane * 4) = o;
}

extern "C" void kernel_launch(void* const* d_in, const int* in_sizes, int n_in,
                              void* d_out, int out_size, void* d_ws, size_t ws_size,
                              hipStream_t stream) {
  const void* feat = d_in[0];
  const int* ei = (const int*)d_in[1];
  const void* indeg = d_in[2];
  const void* ws0 = d_in[3]; const void* wn0 = d_in[4]; const void* b0 = d_in[5];
  const void* ws1 = d_in[6]; const void* wn1 = d_in[7]; const void* b1 = d_in[8];
  const void* ws2 = d_in[9]; const void* wn2 = d_in[10]; const void* b2 = d_in[11];
  const void* g0 = d_in[12]; const void* be0 = d_in[13];
  const void* g1 = d_in[14]; const void* be1 = d_in[15];
  const int* src = ei;
  const int* dst = ei + NE;

  unsigned short* featbf = (unsigned short*)d_ws;                 // 25.6 MB
  unsigned short* aggbf  = featbf + (size_t)NN * 256;             // 25.6 MB
  unsigned short* hbf    = aggbf + (size_t)NN * 256;              // 25.6 MB
  float* pre = (float*)(hbf + (size_t)NN * 256);                  // 51.2 MB
  unsigned short* Bt0 = (unsigned short*)(pre + (size_t)NN * 256);
  unsigned short* Bt1 = Bt0 + 256 * 512;
  unsigned short* Bt2 = Bt1 + 256 * 512;
  int* flag = (int*)(Bt2 + 128 * 512);
  int* bsum = flag + 1;     // NBLK
  int* boff = bsum + 256;   // 256

  // CSR scratch in d_out (3.8 MB of 25.6 MB); last use precedes final GEMM.
  int* counts = (int*)d_out;
  int* rowptr = counts + NN;
  int* cursor = rowptr + NN + 1;
  int* csr_src = cursor + NN;

  dim3 blk(256);
  dim3 gE((NE + 255) / 256);
  dim3 gRow(12500);
  dim3 gG(391, 2);
  dim3 gG2(391, 1);

  detect_kernel<<<1, 64, 0, stream>>>(feat, flag);
  conv_feat_kernel<<<12500, blk, 0, stream>>>(feat, featbf, flag);
  conv_w_kernel<256><<<512, blk, 0, stream>>>(ws0, wn0, Bt0, flag);
  conv_w_kernel<256><<<512, blk, 0, stream>>>(ws1, wn1, Bt1, flag);
  conv_w_kernel<128><<<256, blk, 0, stream>>>(ws2, wn2, Bt2, flag);

  hipMemsetAsync(counts, 0, NN * sizeof(int), stream);
  count_kernel<<<gE, blk, 0, stream>>>(dst, counts);
  bsum_kernel<<<NBLK, blk, 0, stream>>>(counts, bsum);
  bscan_kernel<<<1, blk, 0, stream>>>(bsum, boff);
  rowptr_kernel<<<NBLK, blk, 0, stream>>>(counts, boff, rowptr, cursor);
  fill_kernel<<<gE, blk, 0, stream>>>(src, dst, cursor, csr_src);

  // layer 0
  gather_mean_kernel<<<gRow, blk, 0, stream>>>(featbf, rowptr, csr_src, indeg, aggbf, flag);
  gemm_mfma_kernel<256, false><<<gG, blk, 0, stream>>>(featbf, aggbf, Bt0, b0, pre, flag);
  ln_relu_kernel<<<gRow, blk, 0, stream>>>(pre, hbf, g0, be0, flag);
  // layer 1
  gather_mean_kernel<<<gRow, blk, 0, stream>>>(hbf, rowptr, csr_src, indeg, aggbf, flag);
  gemm_mfma_kernel<256, false><<<gG, blk, 0, stream>>>(hbf, aggbf, Bt1, b1, pre, flag);
  ln_relu_kernel<<<gRow, blk, 0, stream>>>(pre, hbf, g1, be1, flag);
  // layer 2 (no LN/ReLU) -> d_out
  gather_mean_kernel<<<gRow, blk, 0, stream>>>(hbf, rowptr, csr_src, indeg, aggbf, flag);
  gemm_mfma_kernel<128, true><<<gG2, blk, 0, stream>>>(hbf, aggbf, Bt2, b2, d_out, flag);
}